// Round 1
// baseline (71.593 us; speedup 1.0000x reference)
//
#include <hip/hip_runtime.h>

#define DIM   4096
#define BATCH 8192
// Layout: wave = 1 row. Thread t holds elements e = 256*j + 4*t + i  (j=0..15, i=0..3).
// Layer L pairs e with e^(1<<L); coeff index = (4096 - (4096>>L)) + (e >> (L+1)).
//   L0..L1 : within float4 (i axis)           — register FMAs
//   L2..L7 : lane distance 1,2,4,8,16,32      — __shfl_xor
//   L8..L11: register index j distance 1,2,4,8 — register FMAs, wave-uniform coeffs

__device__ __forceinline__ void rot2(float& lo, float& hi, float a, float b) {
    float l = lo, h = hi;
    lo = fmaf(a, l,  b * h);   // top =  a*x0 + b*x1
    hi = fmaf(a, h, -b * l);   // bot = -b*x0 + a*x1
}

__device__ __forceinline__ void rot4(float4& lo, float4& hi, float a, float b) {
    rot2(lo.x, hi.x, a, b);
    rot2(lo.y, hi.y, a, b);
    rot2(lo.z, hi.z, a, b);
    rot2(lo.w, hi.w, a, b);
}

template<bool PACKED>
__device__ __forceinline__ float2 coef(const float* __restrict__ af,
                                       const float* __restrict__ bf,
                                       const float2* __restrict__ ab, int c) {
    if constexpr (PACKED) return ab[c];
    else                  return make_float2(af[c], bf[c]);
}

template<int M, int BASE, int JSHIFT, int LANESHIFT, bool PACKED>
__device__ __forceinline__ void shuf_layer(float4* v, int lane,
                                           const float* __restrict__ af,
                                           const float* __restrict__ bf,
                                           const float2* __restrict__ ab) {
    #pragma unroll
    for (int j = 0; j < 16; ++j) {
        const int c = BASE + (j << JSHIFT) + (lane >> LANESHIFT);
        float2 q = coef<PACKED>(af, bf, ab, c);
        const float sb = (lane & M) ? -q.y : q.y;   // lower half: +b*recv ; upper half: -b*recv
        v[j].x = fmaf(q.x, v[j].x, sb * __shfl_xor(v[j].x, M, 64));
        v[j].y = fmaf(q.x, v[j].y, sb * __shfl_xor(v[j].y, M, 64));
        v[j].z = fmaf(q.x, v[j].z, sb * __shfl_xor(v[j].z, M, 64));
        v[j].w = fmaf(q.x, v[j].w, sb * __shfl_xor(v[j].w, M, 64));
    }
}

template<bool PACKED>
__global__ __launch_bounds__(256)
void bfly_kernel(const float* __restrict__ x,
                 const float* __restrict__ af,
                 const float* __restrict__ bf,
                 const float2* __restrict__ ab,
                 float* __restrict__ out) {
    const int lane = threadIdx.x & 63;
    const int wave = threadIdx.x >> 6;
    const int row  = blockIdx.x * 4 + wave;

    const float4* __restrict__ xr = reinterpret_cast<const float4*>(x + (size_t)row * DIM);
    float4* __restrict__ orow     = reinterpret_cast<float4*>(out + (size_t)row * DIM);

    float4 v[16];
    #pragma unroll
    for (int j = 0; j < 16; ++j) v[j] = xr[64 * j + lane];

    // ---- L0 (bs=1): pairs (x,y) and (z,w); coeffs c0=128j+2*lane, c0+1 ----
    #pragma unroll
    for (int j = 0; j < 16; ++j) {
        float a0, b0, a1, b1;
        if constexpr (PACKED) {
            float4 q = reinterpret_cast<const float4*>(ab)[64 * j + lane]; // (a0,b0,a1,b1)
            a0 = q.x; b0 = q.y; a1 = q.z; b1 = q.w;
        } else {
            float2 aa = *reinterpret_cast<const float2*>(af + 128 * j + 2 * lane);
            float2 bb = *reinterpret_cast<const float2*>(bf + 128 * j + 2 * lane);
            a0 = aa.x; b0 = bb.x; a1 = aa.y; b1 = bb.y;
        }
        rot2(v[j].x, v[j].y, a0, b0);
        rot2(v[j].z, v[j].w, a1, b1);
    }

    // ---- L1 (bs=2): pairs (x,z),(y,w); c = 2048 + 64j + lane ----
    #pragma unroll
    for (int j = 0; j < 16; ++j) {
        float2 q = coef<PACKED>(af, bf, ab, 2048 + 64 * j + lane);
        rot2(v[j].x, v[j].z, q.x, q.y);
        rot2(v[j].y, v[j].w, q.x, q.y);
    }

    // ---- L2..L7: shuffle layers ----
    shuf_layer< 1, 3072, 5, 1, PACKED>(v, lane, af, bf, ab);   // bs=4
    shuf_layer< 2, 3584, 4, 2, PACKED>(v, lane, af, bf, ab);   // bs=8
    shuf_layer< 4, 3840, 3, 3, PACKED>(v, lane, af, bf, ab);   // bs=16
    shuf_layer< 8, 3968, 2, 4, PACKED>(v, lane, af, bf, ab);   // bs=32
    shuf_layer<16, 4032, 1, 5, PACKED>(v, lane, af, bf, ab);   // bs=64
    shuf_layer<32, 4064, 0, 6, PACKED>(v, lane, af, bf, ab);   // bs=128

    // ---- L8 (bs=256): pairs (j, j+1), j even; c = 4080 + (j>>1) (wave-uniform) ----
    #pragma unroll
    for (int j = 0; j < 16; j += 2) {
        float2 q = coef<PACKED>(af, bf, ab, 4080 + (j >> 1));
        rot4(v[j], v[j + 1], q.x, q.y);
    }
    // ---- L9 (bs=512): pairs (j, j+2), j in {0,1,4,5,8,9,12,13}; c = 4088 + (j>>2) ----
    #pragma unroll
    for (int jj = 0; jj < 8; ++jj) {
        const int j = ((jj >> 1) << 2) | (jj & 1);
        float2 q = coef<PACKED>(af, bf, ab, 4088 + (j >> 2));
        rot4(v[j], v[j + 2], q.x, q.y);
    }
    // ---- L10 (bs=1024): pairs (j, j+4), j in {0..3, 8..11}; c = 4092 + (j>>3) ----
    #pragma unroll
    for (int jj = 0; jj < 8; ++jj) {
        const int j = ((jj >> 2) << 3) | (jj & 3);
        float2 q = coef<PACKED>(af, bf, ab, 4092 + (j >> 3));
        rot4(v[j], v[j + 4], q.x, q.y);
    }
    // ---- L11 (bs=2048): pairs (j, j+8), j=0..7; c = 4094 ----
    {
        float2 q = coef<PACKED>(af, bf, ab, 4094);
        #pragma unroll
        for (int j = 0; j < 8; ++j) rot4(v[j], v[j + 8], q.x, q.y);
    }

    #pragma unroll
    for (int j = 0; j < 16; ++j) orow[64 * j + lane] = v[j];
}

__global__ void pack_ab_kernel(const float* __restrict__ af,
                               const float* __restrict__ bf,
                               float2* __restrict__ ab) {
    int i = blockIdx.x * 256 + threadIdx.x;
    if (i < DIM - 1) ab[i] = make_float2(af[i], bf[i]);
}

extern "C" void kernel_launch(void* const* d_in, const int* in_sizes, int n_in,
                              void* d_out, int out_size, void* d_ws, size_t ws_size,
                              hipStream_t stream) {
    const float* x  = (const float*)d_in[0];
    const float* af = (const float*)d_in[1];
    const float* bf = (const float*)d_in[2];
    float* out      = (float*)d_out;

    const bool packed = (d_ws != nullptr) && (ws_size >= (size_t)(DIM - 1) * sizeof(float2));
    if (packed) {
        float2* ab = (float2*)d_ws;
        hipLaunchKernelGGL(pack_ab_kernel, dim3(16), dim3(256), 0, stream, af, bf, ab);
        hipLaunchKernelGGL((bfly_kernel<true>),  dim3(BATCH / 4), dim3(256), 0, stream,
                           x, af, bf, ab, out);
    } else {
        hipLaunchKernelGGL((bfly_kernel<false>), dim3(BATCH / 4), dim3(256), 0, stream,
                           x, af, bf, nullptr, out);
    }
}